// Round 2
// baseline (211.888 us; speedup 1.0000x reference)
//
#include <hip/hip_runtime.h>
#include <hip/hip_bf16.h>
#include <cmath>

typedef __bf16 bf16_t;
typedef __bf16 bf16x8 __attribute__((ext_vector_type(8)));
typedef __bf16 bf16x4 __attribute__((ext_vector_type(4)));
typedef float f32x4 __attribute__((ext_vector_type(4)));

#define QLEN 2048
#define DMODEL 512
#define NH 8
#define DKV 64
#define INNER 512

// ---------- prep: f32 -> (hi, lo) bf16 split ----------
__global__ __launch_bounds__(256) void cvt_split(const float* __restrict__ in,
                                                 bf16_t* __restrict__ hi,
                                                 bf16_t* __restrict__ lo, int n4) {
  int i = blockIdx.x * 256 + threadIdx.x;
  if (i >= n4) return;
  float4 v = reinterpret_cast<const float4*>(in)[i];
  bf16x4 h, l;
  #pragma unroll
  for (int j = 0; j < 4; ++j) {
    float x = (&v.x)[j];
    bf16_t hb = (bf16_t)x;
    h[j] = hb;
    l[j] = (bf16_t)(x - (float)hb);
  }
  reinterpret_cast<bf16x4*>(hi)[i] = h;
  reinterpret_cast<bf16x4*>(lo)[i] = l;
}

// ---------- prep: weight transpose + hi/lo split: Wt[n][k] = W[k][n] ----------
__global__ __launch_bounds__(256) void transpose512_split(const float* __restrict__ W,
                                                          bf16_t* __restrict__ Whi,
                                                          bf16_t* __restrict__ Wlo) {
  __shared__ float tile[32][33];
  int bk = blockIdx.x * 32, bn = blockIdx.y * 32;
  int tx = threadIdx.x, ty = threadIdx.y;
  #pragma unroll
  for (int i = 0; i < 32; i += 8)
    tile[ty + i][tx] = W[(size_t)(bk + ty + i) * DMODEL + bn + tx];
  __syncthreads();
  #pragma unroll
  for (int i = 0; i < 32; i += 8) {
    float v = tile[tx][ty + i];
    bf16_t hb = (bf16_t)v;
    size_t o = (size_t)(bn + ty + i) * DMODEL + bk + tx;
    Whi[o] = hb;
    Wlo[o] = (bf16_t)(v - (float)hb);
  }
}

// ---------- single-pass bf16 MFMA GEMM (V projection, output projection) ----------
// MODE 1: bf16 transposed (V): C[(b*512+n)*2048+s]; MODE 2: f32 natural.
template<int MODE>
__global__ __launch_bounds__(256) void gemm128(const bf16_t* __restrict__ A,
                                               const bf16_t* __restrict__ Bt,
                                               bf16_t* __restrict__ Cb,
                                               float* __restrict__ Cf) {
  __shared__ bf16_t sA[128 * 72];
  __shared__ bf16_t sB[128 * 72];
  const int m0 = blockIdx.x * 128, n0 = blockIdx.y * 128;
  const int tid = threadIdx.x;
  const int lane = tid & 63, w = tid >> 6;
  const int wr = (w >> 1) * 64, wc = (w & 1) * 64;
  const int l16 = lane & 15, lg = lane >> 4;

  f32x4 acc[4][4] = {};

  for (int k0 = 0; k0 < DMODEL; k0 += 64) {
    #pragma unroll
    for (int i = 0; i < 4; ++i) {
      int chunk = tid + i * 256;
      int row = chunk >> 3, c8 = (chunk & 7) * 8;
      *reinterpret_cast<bf16x8*>(&sA[row * 72 + c8]) =
          *reinterpret_cast<const bf16x8*>(&A[(size_t)(m0 + row) * DMODEL + k0 + c8]);
      *reinterpret_cast<bf16x8*>(&sB[row * 72 + c8]) =
          *reinterpret_cast<const bf16x8*>(&Bt[(size_t)(n0 + row) * DMODEL + k0 + c8]);
    }
    __syncthreads();
    #pragma unroll
    for (int ks = 0; ks < 2; ++ks) {
      bf16x8 af[4], bfr[4];
      #pragma unroll
      for (int i = 0; i < 4; ++i)
        af[i] = *reinterpret_cast<const bf16x8*>(&sA[(wr + i * 16 + l16) * 72 + ks * 32 + lg * 8]);
      #pragma unroll
      for (int j = 0; j < 4; ++j)
        bfr[j] = *reinterpret_cast<const bf16x8*>(&sB[(wc + j * 16 + l16) * 72 + ks * 32 + lg * 8]);
      #pragma unroll
      for (int i = 0; i < 4; ++i)
        #pragma unroll
        for (int j = 0; j < 4; ++j)
          acc[i][j] = __builtin_amdgcn_mfma_f32_16x16x32_bf16(af[i], bfr[j], acc[i][j], 0, 0, 0);
    }
    __syncthreads();
  }

  #pragma unroll
  for (int i = 0; i < 4; ++i)
    #pragma unroll
    for (int j = 0; j < 4; ++j)
      #pragma unroll
      for (int r = 0; r < 4; ++r) {
        int m = m0 + wr + i * 16 + lg * 4 + r;
        int n = n0 + wc + j * 16 + l16;
        float v = acc[i][j][r];
        if (MODE == 1) {
          int b = m >> 11, s = m & (QLEN - 1);
          Cb[(size_t)(b * INNER + n) * QLEN + s] = (bf16_t)v;
        } else {
          Cf[(size_t)m * DMODEL + n] = v;
        }
      }
}

// ---------- 3-pass split GEMM: C = (Ah+Al) @ (Bh+Bl)^T, writes hi/lo pair ----------
__global__ __launch_bounds__(256) void gemm128_split(const bf16_t* __restrict__ Ah,
                                                     const bf16_t* __restrict__ Al,
                                                     const bf16_t* __restrict__ Bh,
                                                     const bf16_t* __restrict__ Bl,
                                                     bf16_t* __restrict__ Ch,
                                                     bf16_t* __restrict__ Cl) {
  __shared__ bf16_t sAh[128 * 72];
  __shared__ bf16_t sAl[128 * 72];
  __shared__ bf16_t sBh[128 * 72];
  __shared__ bf16_t sBl[128 * 72];
  const int m0 = blockIdx.x * 128, n0 = blockIdx.y * 128;
  const int tid = threadIdx.x;
  const int lane = tid & 63, w = tid >> 6;
  const int wr = (w >> 1) * 64, wc = (w & 1) * 64;
  const int l16 = lane & 15, lg = lane >> 4;

  f32x4 acc[4][4] = {};

  for (int k0 = 0; k0 < DMODEL; k0 += 64) {
    #pragma unroll
    for (int i = 0; i < 4; ++i) {
      int chunk = tid + i * 256;
      int row = chunk >> 3, c8 = (chunk & 7) * 8;
      size_t ga = (size_t)(m0 + row) * DMODEL + k0 + c8;
      size_t gb = (size_t)(n0 + row) * DMODEL + k0 + c8;
      *reinterpret_cast<bf16x8*>(&sAh[row * 72 + c8]) = *reinterpret_cast<const bf16x8*>(&Ah[ga]);
      *reinterpret_cast<bf16x8*>(&sAl[row * 72 + c8]) = *reinterpret_cast<const bf16x8*>(&Al[ga]);
      *reinterpret_cast<bf16x8*>(&sBh[row * 72 + c8]) = *reinterpret_cast<const bf16x8*>(&Bh[gb]);
      *reinterpret_cast<bf16x8*>(&sBl[row * 72 + c8]) = *reinterpret_cast<const bf16x8*>(&Bl[gb]);
    }
    __syncthreads();
    #pragma unroll
    for (int ks = 0; ks < 2; ++ks) {
      bf16x8 ah[4], al[4], bh[4], bl[4];
      #pragma unroll
      for (int i = 0; i < 4; ++i) {
        int ro = (wr + i * 16 + l16) * 72 + ks * 32 + lg * 8;
        ah[i] = *reinterpret_cast<const bf16x8*>(&sAh[ro]);
        al[i] = *reinterpret_cast<const bf16x8*>(&sAl[ro]);
      }
      #pragma unroll
      for (int j = 0; j < 4; ++j) {
        int ro = (wc + j * 16 + l16) * 72 + ks * 32 + lg * 8;
        bh[j] = *reinterpret_cast<const bf16x8*>(&sBh[ro]);
        bl[j] = *reinterpret_cast<const bf16x8*>(&sBl[ro]);
      }
      #pragma unroll
      for (int i = 0; i < 4; ++i)
        #pragma unroll
        for (int j = 0; j < 4; ++j) {
          acc[i][j] = __builtin_amdgcn_mfma_f32_16x16x32_bf16(ah[i], bh[j], acc[i][j], 0, 0, 0);
          acc[i][j] = __builtin_amdgcn_mfma_f32_16x16x32_bf16(ah[i], bl[j], acc[i][j], 0, 0, 0);
          acc[i][j] = __builtin_amdgcn_mfma_f32_16x16x32_bf16(al[i], bh[j], acc[i][j], 0, 0, 0);
        }
    }
    __syncthreads();
  }

  #pragma unroll
  for (int i = 0; i < 4; ++i)
    #pragma unroll
    for (int j = 0; j < 4; ++j)
      #pragma unroll
      for (int r = 0; r < 4; ++r) {
        int m = m0 + wr + i * 16 + lg * 4 + r;
        int n = n0 + wc + j * 16 + l16;
        float v = acc[i][j][r];
        bf16_t hb = (bf16_t)v;
        size_t o = (size_t)m * INNER + n;
        Ch[o] = hb;
        Cl[o] = (bf16_t)(v - (float)hb);
      }
}

// ---------- attention helpers ----------
__device__ __forceinline__ float redmax16(float v) {
  v = fmaxf(v, __shfl_xor(v, 1));
  v = fmaxf(v, __shfl_xor(v, 2));
  v = fmaxf(v, __shfl_xor(v, 4));
  v = fmaxf(v, __shfl_xor(v, 8));
  return v;
}
__device__ __forceinline__ float redsum16(float v) {
  v += __shfl_xor(v, 1);
  v += __shfl_xor(v, 2);
  v += __shfl_xor(v, 4);
  v += __shfl_xor(v, 8);
  return v;
}
// exact integer thresholds for T5 bucket (bidirectional, 32 buckets, maxdist 128)
__device__ __forceinline__ int t5_bucket_abs(int n) {
  if (n < 8)  return n;
  if (n < 12) return 8;
  if (n < 16) return 9;
  if (n < 23) return 10;
  if (n < 32) return 11;
  if (n < 46) return 12;
  if (n < 64) return 13;
  if (n < 91) return 14;
  return 15;
}

// ---------- flash attention with split-precision QK^T ----------
__global__ __launch_bounds__(256) void attn_kernel(const bf16_t* __restrict__ Qh,
                                                   const bf16_t* __restrict__ Ql,
                                                   const bf16_t* __restrict__ Kh,
                                                   const bf16_t* __restrict__ Kl,
                                                   const bf16_t* __restrict__ Vt,
                                                   const float* __restrict__ relb,
                                                   bf16_t* __restrict__ ctx) {
  __shared__ bf16_t sKh[64 * 72];
  __shared__ bf16_t sKl[64 * 72];
  __shared__ bf16_t sV[64 * 72];
  __shared__ bf16_t sP[128 * 72];
  __shared__ float sBiasH[32];

  const int qt = blockIdx.x, h = blockIdx.y, b = blockIdx.z;
  const int tid = threadIdx.x, lane = tid & 63, w = tid >> 6;
  const int l16 = lane & 15, lg = lane >> 4;
  const int q0 = qt * 128;
  const int wq = w * 32;

  if (tid < 32) sBiasH[tid] = relb[tid * NH + h];

  // Q fragments (hi + lo), held in registers
  bf16x8 qh[2][2], ql[2][2];
  #pragma unroll
  for (int mi = 0; mi < 2; ++mi)
    #pragma unroll
    for (int ks = 0; ks < 2; ++ks) {
      size_t o = (size_t)(b * QLEN + q0 + wq + mi * 16 + l16) * INNER + h * DKV + ks * 32 + lg * 8;
      qh[mi][ks] = *reinterpret_cast<const bf16x8*>(&Qh[o]);
      ql[mi][ks] = *reinterpret_cast<const bf16x8*>(&Ql[o]);
    }

  f32x4 acc[2][4] = {};
  float mrow[2][4], lrow[2][4];
  #pragma unroll
  for (int mi = 0; mi < 2; ++mi)
    #pragma unroll
    for (int r = 0; r < 4; ++r) { mrow[mi][r] = -INFINITY; lrow[mi][r] = 0.f; }

  for (int kt = 0; kt < QLEN / 64; ++kt) {
    const int k0 = kt * 64;
    #pragma unroll
    for (int i = 0; i < 2; ++i) {
      int chunk = tid + i * 256;
      int row = chunk >> 3, c8 = (chunk & 7) * 8;
      size_t gk = (size_t)(b * QLEN + k0 + row) * INNER + h * DKV + c8;
      *reinterpret_cast<bf16x8*>(&sKh[row * 72 + c8]) = *reinterpret_cast<const bf16x8*>(&Kh[gk]);
      *reinterpret_cast<bf16x8*>(&sKl[row * 72 + c8]) = *reinterpret_cast<const bf16x8*>(&Kl[gk]);
      *reinterpret_cast<bf16x8*>(&sV[row * 72 + c8]) =
          *reinterpret_cast<const bf16x8*>(&Vt[(size_t)((b * NH + h) * DKV + row) * QLEN + k0 + c8]);
    }
    __syncthreads();

    // S = Q K^T in 3 passes (hi*hi + hi*lo + lo*hi)
    f32x4 s[2][4] = {};
    #pragma unroll
    for (int ks = 0; ks < 2; ++ks) {
      bf16x8 kh[4], kl[4];
      #pragma unroll
      for (int ni = 0; ni < 4; ++ni) {
        int ro = (ni * 16 + l16) * 72 + ks * 32 + lg * 8;
        kh[ni] = *reinterpret_cast<const bf16x8*>(&sKh[ro]);
        kl[ni] = *reinterpret_cast<const bf16x8*>(&sKl[ro]);
      }
      #pragma unroll
      for (int mi = 0; mi < 2; ++mi)
        #pragma unroll
        for (int ni = 0; ni < 4; ++ni) {
          s[mi][ni] = __builtin_amdgcn_mfma_f32_16x16x32_bf16(qh[mi][ks], kh[ni], s[mi][ni], 0, 0, 0);
          s[mi][ni] = __builtin_amdgcn_mfma_f32_16x16x32_bf16(qh[mi][ks], kl[ni], s[mi][ni], 0, 0, 0);
          s[mi][ni] = __builtin_amdgcn_mfma_f32_16x16x32_bf16(ql[mi][ks], kh[ni], s[mi][ni], 0, 0, 0);
        }
    }

    // + relative position bias
    const int dmin = q0 - (k0 + 63);
    const int dmax = q0 + 127 - k0;
    if (dmin >= 91) {
      const float bias = sBiasH[15];
      #pragma unroll
      for (int mi = 0; mi < 2; ++mi)
        #pragma unroll
        for (int ni = 0; ni < 4; ++ni)
          #pragma unroll
          for (int r = 0; r < 4; ++r) s[mi][ni][r] += bias;
    } else if (dmax <= -91) {
      const float bias = sBiasH[31];
      #pragma unroll
      for (int mi = 0; mi < 2; ++mi)
        #pragma unroll
        for (int ni = 0; ni < 4; ++ni)
          #pragma unroll
          for (int r = 0; r < 4; ++r) s[mi][ni][r] += bias;
    } else {
      #pragma unroll
      for (int mi = 0; mi < 2; ++mi)
        #pragma unroll
        for (int ni = 0; ni < 4; ++ni) {
          int kcol = k0 + ni * 16 + l16;
          #pragma unroll
          for (int r = 0; r < 4; ++r) {
            int qrow = q0 + wq + mi * 16 + lg * 4 + r;
            int d = qrow - kcol;
            int n = d < 0 ? -d : d;
            int bk = t5_bucket_abs(n) + (d < 0 ? 16 : 0);
            s[mi][ni][r] += sBiasH[bk];
          }
        }
    }

    // online softmax
    #pragma unroll
    for (int mi = 0; mi < 2; ++mi)
      #pragma unroll
      for (int r = 0; r < 4; ++r) {
        float mx = fmaxf(fmaxf(s[mi][0][r], s[mi][1][r]), fmaxf(s[mi][2][r], s[mi][3][r]));
        mx = redmax16(mx);
        float mnew = fmaxf(mrow[mi][r], mx);
        float alpha = __expf(mrow[mi][r] - mnew);
        mrow[mi][r] = mnew;
        float ps = 0.f;
        #pragma unroll
        for (int ni = 0; ni < 4; ++ni) {
          float p = __expf(s[mi][ni][r] - mnew);
          s[mi][ni][r] = p;
          ps += p;
        }
        ps = redsum16(ps);
        lrow[mi][r] = lrow[mi][r] * alpha + ps;
        #pragma unroll
        for (int di = 0; di < 4; ++di) acc[mi][di][r] *= alpha;
      }

    // P -> LDS (bf16)
    #pragma unroll
    for (int mi = 0; mi < 2; ++mi)
      #pragma unroll
      for (int ni = 0; ni < 4; ++ni)
        #pragma unroll
        for (int r = 0; r < 4; ++r)
          sP[(wq + mi * 16 + lg * 4 + r) * 72 + ni * 16 + l16] = (bf16_t)s[mi][ni][r];
    __syncthreads();

    // acc += P * V
    #pragma unroll
    for (int ks = 0; ks < 2; ++ks) {
      bf16x8 pf[2], vf[4];
      #pragma unroll
      for (int mi = 0; mi < 2; ++mi)
        pf[mi] = *reinterpret_cast<const bf16x8*>(&sP[(wq + mi * 16 + l16) * 72 + ks * 32 + lg * 8]);
      #pragma unroll
      for (int di = 0; di < 4; ++di)
        vf[di] = *reinterpret_cast<const bf16x8*>(&sV[(di * 16 + l16) * 72 + ks * 32 + lg * 8]);
      #pragma unroll
      for (int mi = 0; mi < 2; ++mi)
        #pragma unroll
        for (int di = 0; di < 4; ++di)
          acc[mi][di] = __builtin_amdgcn_mfma_f32_16x16x32_bf16(pf[mi], vf[di], acc[mi][di], 0, 0, 0);
    }
    __syncthreads();
  }

  #pragma unroll
  for (int mi = 0; mi < 2; ++mi)
    #pragma unroll
    for (int di = 0; di < 4; ++di)
      #pragma unroll
      for (int r = 0; r < 4; ++r) {
        int qrow = q0 + wq + mi * 16 + lg * 4 + r;
        float v = acc[mi][di][r] / lrow[mi][r];
        ctx[(size_t)(b * QLEN + qrow) * INNER + h * DKV + di * 16 + l16] = (bf16_t)v;
      }
}

extern "C" void kernel_launch(void* const* d_in, const int* in_sizes, int n_in,
                              void* d_out, int out_size, void* d_ws, size_t ws_size,
                              hipStream_t stream) {
  const float* X    = (const float*)d_in[0];
  const float* Wq   = (const float*)d_in[1];
  const float* Wk   = (const float*)d_in[2];
  const float* Wv   = (const float*)d_in[3];
  const float* Wo   = (const float*)d_in[4];
  const float* relb = (const float*)d_in[5];
  float* out = (float*)d_out;

  const size_t WSZ = 262144, XSZ = 2097152;
  bf16_t* ws   = (bf16_t*)d_ws;
  bf16_t* Wq_h = ws;              bf16_t* Wq_l = Wq_h + WSZ;
  bf16_t* Wk_h = Wq_l + WSZ;      bf16_t* Wk_l = Wk_h + WSZ;
  bf16_t* Wv_h = Wk_l + WSZ;      bf16_t* Wv_l = Wv_h + WSZ;
  bf16_t* Wo_h = Wv_l + WSZ;      bf16_t* Wo_l = Wo_h + WSZ;
  bf16_t* Xh   = Wo_l + WSZ;      bf16_t* Xl   = Xh + XSZ;
  bf16_t* Q_h  = Xl + XSZ;        bf16_t* Q_l  = Q_h + XSZ;
  bf16_t* K_h  = Q_l + XSZ;       bf16_t* K_l  = K_h + XSZ;
  bf16_t* Vt   = Xl;              // alias: Xl dead after K projection
  bf16_t* ctx  = Xh;              // alias: Xh dead after V projection

  dim3 tb(32, 8), tg(16, 16);
  transpose512_split<<<tg, tb, 0, stream>>>(Wq, Wq_h, Wq_l);
  transpose512_split<<<tg, tb, 0, stream>>>(Wk, Wk_h, Wk_l);
  transpose512_split<<<tg, tb, 0, stream>>>(Wv, Wv_h, Wv_l);
  transpose512_split<<<tg, tb, 0, stream>>>(Wo, Wo_h, Wo_l);

  int n4 = (2 * QLEN * DMODEL) / 4;
  cvt_split<<<n4 / 256, 256, 0, stream>>>(X, Xh, Xl, n4);

  dim3 gg(32, 4);
  gemm128_split<<<gg, 256, 0, stream>>>(Xh, Xl, Wq_h, Wq_l, Q_h, Q_l);
  gemm128_split<<<gg, 256, 0, stream>>>(Xh, Xl, Wk_h, Wk_l, K_h, K_l);
  gemm128<1><<<gg, 256, 0, stream>>>(Xh, Wv_h, Vt, nullptr);

  attn_kernel<<<dim3(16, NH, 2), 256, 0, stream>>>(Q_h, Q_l, K_h, K_l, Vt, relb, ctx);

  gemm128<2><<<gg, 256, 0, stream>>>(ctx, Wo_h, nullptr, out);
}

// Round 3
// 170.824 us; speedup vs baseline: 1.2404x; 1.2404x over previous
//
#include <hip/hip_runtime.h>
#include <hip/hip_bf16.h>
#include <cmath>

typedef __bf16 bf16_t;
typedef __bf16 bf16x8 __attribute__((ext_vector_type(8)));
typedef __bf16 bf16x4 __attribute__((ext_vector_type(4)));
typedef float f32x4 __attribute__((ext_vector_type(4)));

#define QLEN 2048
#define DMODEL 512
#define NH 8
#define DKV 64
#define INNER 512

// ---------- prep: f32 -> (hi, lo) bf16 split ----------
__global__ __launch_bounds__(256) void cvt_split(const float* __restrict__ in,
                                                 bf16_t* __restrict__ hi,
                                                 bf16_t* __restrict__ lo, int n4) {
  int i = blockIdx.x * 256 + threadIdx.x;
  if (i >= n4) return;
  float4 v = reinterpret_cast<const float4*>(in)[i];
  bf16x4 h, l;
  #pragma unroll
  for (int j = 0; j < 4; ++j) {
    float x = (&v.x)[j];
    bf16_t hb = (bf16_t)x;
    h[j] = hb;
    l[j] = (bf16_t)(x - (float)hb);
  }
  reinterpret_cast<bf16x4*>(hi)[i] = h;
  reinterpret_cast<bf16x4*>(lo)[i] = l;
}

// ---------- prep: weight transpose + hi/lo split: Wt[n][k] = W[k][n] ----------
__global__ __launch_bounds__(256) void transpose512_split(const float* __restrict__ W,
                                                          bf16_t* __restrict__ Whi,
                                                          bf16_t* __restrict__ Wlo) {
  __shared__ float tile[32][33];
  int bk = blockIdx.x * 32, bn = blockIdx.y * 32;
  int tx = threadIdx.x, ty = threadIdx.y;
  #pragma unroll
  for (int i = 0; i < 32; i += 8)
    tile[ty + i][tx] = W[(size_t)(bk + ty + i) * DMODEL + bn + tx];
  __syncthreads();
  #pragma unroll
  for (int i = 0; i < 32; i += 8) {
    float v = tile[tx][ty + i];
    bf16_t hb = (bf16_t)v;
    size_t o = (size_t)(bn + ty + i) * DMODEL + bk + tx;
    Whi[o] = hb;
    Wlo[o] = (bf16_t)(v - (float)hb);
  }
}

// ---------- single-pass bf16 MFMA GEMM ----------
// MODE 1: bf16 transposed (V): C[(b*512+n)*2048+s]; MODE 2: f32 natural.
template<int MODE>
__global__ __launch_bounds__(256) void gemm128(const bf16_t* __restrict__ A,
                                               const bf16_t* __restrict__ Bt,
                                               bf16_t* __restrict__ Cb,
                                               float* __restrict__ Cf) {
  __shared__ bf16_t sA[128 * 72];
  __shared__ bf16_t sB[128 * 72];
  const int m0 = blockIdx.x * 128, n0 = blockIdx.y * 128;
  const int tid = threadIdx.x;
  const int lane = tid & 63, w = tid >> 6;
  const int wr = (w >> 1) * 64, wc = (w & 1) * 64;
  const int l16 = lane & 15, lg = lane >> 4;

  f32x4 acc[4][4] = {};

  for (int k0 = 0; k0 < DMODEL; k0 += 64) {
    #pragma unroll
    for (int i = 0; i < 4; ++i) {
      int chunk = tid + i * 256;
      int row = chunk >> 3, c8 = (chunk & 7) * 8;
      *reinterpret_cast<bf16x8*>(&sA[row * 72 + c8]) =
          *reinterpret_cast<const bf16x8*>(&A[(size_t)(m0 + row) * DMODEL + k0 + c8]);
      *reinterpret_cast<bf16x8*>(&sB[row * 72 + c8]) =
          *reinterpret_cast<const bf16x8*>(&Bt[(size_t)(n0 + row) * DMODEL + k0 + c8]);
    }
    __syncthreads();
    #pragma unroll
    for (int ks = 0; ks < 2; ++ks) {
      bf16x8 af[4], bfr[4];
      #pragma unroll
      for (int i = 0; i < 4; ++i)
        af[i] = *reinterpret_cast<const bf16x8*>(&sA[(wr + i * 16 + l16) * 72 + ks * 32 + lg * 8]);
      #pragma unroll
      for (int j = 0; j < 4; ++j)
        bfr[j] = *reinterpret_cast<const bf16x8*>(&sB[(wc + j * 16 + l16) * 72 + ks * 32 + lg * 8]);
      #pragma unroll
      for (int i = 0; i < 4; ++i)
        #pragma unroll
        for (int j = 0; j < 4; ++j)
          acc[i][j] = __builtin_amdgcn_mfma_f32_16x16x32_bf16(af[i], bfr[j], acc[i][j], 0, 0, 0);
    }
    __syncthreads();
  }

  #pragma unroll
  for (int i = 0; i < 4; ++i)
    #pragma unroll
    for (int j = 0; j < 4; ++j)
      #pragma unroll
      for (int r = 0; r < 4; ++r) {
        int m = m0 + wr + i * 16 + lg * 4 + r;
        int n = n0 + wc + j * 16 + l16;
        float v = acc[i][j][r];
        if (MODE == 1) {
          int b = m >> 11, s = m & (QLEN - 1);
          Cb[(size_t)(b * INNER + n) * QLEN + s] = (bf16_t)v;
        } else {
          Cf[(size_t)m * DMODEL + n] = v;
        }
      }
}

// ---------- 3-pass split GEMM: C = (Ah+Al) @ (Bh+Bl)^T, writes hi/lo pair ----------
__global__ __launch_bounds__(256) void gemm128_split(const bf16_t* __restrict__ Ah,
                                                     const bf16_t* __restrict__ Al,
                                                     const bf16_t* __restrict__ Bh,
                                                     const bf16_t* __restrict__ Bl,
                                                     bf16_t* __restrict__ Ch,
                                                     bf16_t* __restrict__ Cl) {
  __shared__ bf16_t sAh[128 * 72];
  __shared__ bf16_t sAl[128 * 72];
  __shared__ bf16_t sBh[128 * 72];
  __shared__ bf16_t sBl[128 * 72];
  const int m0 = blockIdx.x * 128, n0 = blockIdx.y * 128;
  const int tid = threadIdx.x;
  const int lane = tid & 63, w = tid >> 6;
  const int wr = (w >> 1) * 64, wc = (w & 1) * 64;
  const int l16 = lane & 15, lg = lane >> 4;

  f32x4 acc[4][4] = {};

  for (int k0 = 0; k0 < DMODEL; k0 += 64) {
    #pragma unroll
    for (int i = 0; i < 4; ++i) {
      int chunk = tid + i * 256;
      int row = chunk >> 3, c8 = (chunk & 7) * 8;
      size_t ga = (size_t)(m0 + row) * DMODEL + k0 + c8;
      size_t gb = (size_t)(n0 + row) * DMODEL + k0 + c8;
      *reinterpret_cast<bf16x8*>(&sAh[row * 72 + c8]) = *reinterpret_cast<const bf16x8*>(&Ah[ga]);
      *reinterpret_cast<bf16x8*>(&sAl[row * 72 + c8]) = *reinterpret_cast<const bf16x8*>(&Al[ga]);
      *reinterpret_cast<bf16x8*>(&sBh[row * 72 + c8]) = *reinterpret_cast<const bf16x8*>(&Bh[gb]);
      *reinterpret_cast<bf16x8*>(&sBl[row * 72 + c8]) = *reinterpret_cast<const bf16x8*>(&Bl[gb]);
    }
    __syncthreads();
    #pragma unroll
    for (int ks = 0; ks < 2; ++ks) {
      bf16x8 ah[4], al[4], bh[4], bl[4];
      #pragma unroll
      for (int i = 0; i < 4; ++i) {
        int ro = (wr + i * 16 + l16) * 72 + ks * 32 + lg * 8;
        ah[i] = *reinterpret_cast<const bf16x8*>(&sAh[ro]);
        al[i] = *reinterpret_cast<const bf16x8*>(&sAl[ro]);
      }
      #pragma unroll
      for (int j = 0; j < 4; ++j) {
        int ro = (wc + j * 16 + l16) * 72 + ks * 32 + lg * 8;
        bh[j] = *reinterpret_cast<const bf16x8*>(&sBh[ro]);
        bl[j] = *reinterpret_cast<const bf16x8*>(&sBl[ro]);
      }
      #pragma unroll
      for (int i = 0; i < 4; ++i)
        #pragma unroll
        for (int j = 0; j < 4; ++j) {
          acc[i][j] = __builtin_amdgcn_mfma_f32_16x16x32_bf16(ah[i], bh[j], acc[i][j], 0, 0, 0);
          acc[i][j] = __builtin_amdgcn_mfma_f32_16x16x32_bf16(ah[i], bl[j], acc[i][j], 0, 0, 0);
          acc[i][j] = __builtin_amdgcn_mfma_f32_16x16x32_bf16(al[i], bh[j], acc[i][j], 0, 0, 0);
        }
    }
    __syncthreads();
  }

  #pragma unroll
  for (int i = 0; i < 4; ++i)
    #pragma unroll
    for (int j = 0; j < 4; ++j)
      #pragma unroll
      for (int r = 0; r < 4; ++r) {
        int m = m0 + wr + i * 16 + lg * 4 + r;
        int n = n0 + wc + j * 16 + l16;
        float v = acc[i][j][r];
        bf16_t hb = (bf16_t)v;
        size_t o = (size_t)m * INNER + n;
        Ch[o] = hb;
        Cl[o] = (bf16_t)(v - (float)hb);
      }
}

// ---------- attention helpers ----------
__device__ __forceinline__ float redmax16(float v) {
  v = fmaxf(v, __shfl_xor(v, 1));
  v = fmaxf(v, __shfl_xor(v, 2));
  v = fmaxf(v, __shfl_xor(v, 4));
  v = fmaxf(v, __shfl_xor(v, 8));
  return v;
}
__device__ __forceinline__ float redsum16(float v) {
  v += __shfl_xor(v, 1);
  v += __shfl_xor(v, 2);
  v += __shfl_xor(v, 4);
  v += __shfl_xor(v, 8);
  return v;
}
__device__ __forceinline__ int t5_bucket_abs(int n) {
  if (n < 8)  return n;
  if (n < 12) return 8;
  if (n < 16) return 9;
  if (n < 23) return 10;
  if (n < 32) return 11;
  if (n < 46) return 12;
  if (n < 64) return 13;
  if (n < 91) return 14;
  return 15;
}

// ---------- flash attention v2: QBLK=64, 4 waves x 16 rows, dbuf + async stage ----------
struct StageRegs { bf16x8 kh[2], kl[2], v[2]; };

__device__ __forceinline__ void stage_load(StageRegs& r, const bf16_t* __restrict__ Kh,
                                           const bf16_t* __restrict__ Kl,
                                           const bf16_t* __restrict__ Vt,
                                           int b, int h, int k0, int tid) {
  #pragma unroll
  for (int i = 0; i < 2; ++i) {
    int chunk = tid + i * 256;
    int row = chunk >> 3, c8 = (chunk & 7) * 8;
    size_t gk = (size_t)(b * QLEN + k0 + row) * INNER + h * DKV + c8;
    r.kh[i] = *reinterpret_cast<const bf16x8*>(&Kh[gk]);
    r.kl[i] = *reinterpret_cast<const bf16x8*>(&Kl[gk]);
    r.v[i]  = *reinterpret_cast<const bf16x8*>(
        &Vt[(size_t)((b * NH + h) * DKV + row) * QLEN + k0 + c8]);
  }
}
__device__ __forceinline__ void stage_write(const StageRegs& r, bf16_t* dKh, bf16_t* dKl,
                                            bf16_t* dV, int tid) {
  #pragma unroll
  for (int i = 0; i < 2; ++i) {
    int chunk = tid + i * 256;
    int row = chunk >> 3, c8 = (chunk & 7) * 8;
    *reinterpret_cast<bf16x8*>(&dKh[row * 72 + c8]) = r.kh[i];
    *reinterpret_cast<bf16x8*>(&dKl[row * 72 + c8]) = r.kl[i];
    *reinterpret_cast<bf16x8*>(&dV [row * 72 + c8]) = r.v[i];
  }
}

__global__ __launch_bounds__(256) void attn_kernel(const bf16_t* __restrict__ Qh,
                                                   const bf16_t* __restrict__ Ql,
                                                   const bf16_t* __restrict__ Kh,
                                                   const bf16_t* __restrict__ Kl,
                                                   const bf16_t* __restrict__ Vt,
                                                   const float* __restrict__ relb,
                                                   bf16_t* __restrict__ ctx) {
  __shared__ bf16_t sKh[2][64 * 72];
  __shared__ bf16_t sKl[2][64 * 72];
  __shared__ bf16_t sV [2][64 * 72];
  __shared__ bf16_t sP [64 * 72];
  __shared__ float sBiasH[32];

  const int qt = blockIdx.x, h = blockIdx.y, b = blockIdx.z;
  const int tid = threadIdx.x, lane = tid & 63, w = tid >> 6;
  const int l16 = lane & 15, lg = lane >> 4;
  const int q0 = qt * 64;
  const int wq = w * 16;   // wave-owned q rows [wq, wq+16)

  if (tid < 32) sBiasH[tid] = relb[tid * NH + h];

  // Q fragments (hi + lo), held in registers
  bf16x8 qh[2], ql[2];
  #pragma unroll
  for (int ks = 0; ks < 2; ++ks) {
    size_t o = (size_t)(b * QLEN + q0 + wq + l16) * INNER + h * DKV + ks * 32 + lg * 8;
    qh[ks] = *reinterpret_cast<const bf16x8*>(&Qh[o]);
    ql[ks] = *reinterpret_cast<const bf16x8*>(&Ql[o]);
  }

  f32x4 acc[4] = {};
  float mrow[4], lrow[4];
  #pragma unroll
  for (int r = 0; r < 4; ++r) { mrow[r] = -INFINITY; lrow[r] = 0.f; }

  const int NT = QLEN / 64;
  StageRegs sreg;
  stage_load(sreg, Kh, Kl, Vt, b, h, 0, tid);
  stage_write(sreg, sKh[0], sKl[0], sV[0], tid);
  int cur = 0;

  for (int kt = 0; kt < NT; ++kt) {
    __syncthreads();   // buf[cur] visible; buf[cur^1] free for staging
    const int k0 = kt * 64;
    const bool pf = (kt + 1 < NT);
    if (pf) stage_load(sreg, Kh, Kl, Vt, b, h, k0 + 64, tid);

    // S = Q K^T in 3 passes (hi*hi + hi*lo + lo*hi)
    f32x4 s[4] = {};
    __builtin_amdgcn_s_setprio(1);
    #pragma unroll
    for (int ks = 0; ks < 2; ++ks) {
      bf16x8 kh[4], kl[4];
      #pragma unroll
      for (int ni = 0; ni < 4; ++ni) {
        int ro = (ni * 16 + l16) * 72 + ks * 32 + lg * 8;
        kh[ni] = *reinterpret_cast<const bf16x8*>(&sKh[cur][ro]);
        kl[ni] = *reinterpret_cast<const bf16x8*>(&sKl[cur][ro]);
      }
      #pragma unroll
      for (int ni = 0; ni < 4; ++ni) {
        s[ni] = __builtin_amdgcn_mfma_f32_16x16x32_bf16(qh[ks], kh[ni], s[ni], 0, 0, 0);
        s[ni] = __builtin_amdgcn_mfma_f32_16x16x32_bf16(qh[ks], kl[ni], s[ni], 0, 0, 0);
        s[ni] = __builtin_amdgcn_mfma_f32_16x16x32_bf16(ql[ks], kh[ni], s[ni], 0, 0, 0);
      }
    }
    __builtin_amdgcn_s_setprio(0);

    // + relative position bias
    const int dmin = q0 - (k0 + 63);
    const int dmax = q0 + 63 - k0;
    if (dmin >= 91) {
      const float bias = sBiasH[15];
      #pragma unroll
      for (int ni = 0; ni < 4; ++ni)
        #pragma unroll
        for (int r = 0; r < 4; ++r) s[ni][r] += bias;
    } else if (dmax <= -91) {
      const float bias = sBiasH[31];
      #pragma unroll
      for (int ni = 0; ni < 4; ++ni)
        #pragma unroll
        for (int r = 0; r < 4; ++r) s[ni][r] += bias;
    } else {
      #pragma unroll
      for (int ni = 0; ni < 4; ++ni) {
        int kcol = k0 + ni * 16 + l16;
        #pragma unroll
        for (int r = 0; r < 4; ++r) {
          int qrow = q0 + wq + lg * 4 + r;
          int d = qrow - kcol;
          int n = d < 0 ? -d : d;
          int bk = t5_bucket_abs(n) + (d < 0 ? 16 : 0);
          s[ni][r] += sBiasH[bk];
        }
      }
    }

    // online softmax (rows live in 16-lane groups)
    #pragma unroll
    for (int r = 0; r < 4; ++r) {
      float mx = fmaxf(fmaxf(s[0][r], s[1][r]), fmaxf(s[2][r], s[3][r]));
      mx = redmax16(mx);
      float mnew = fmaxf(mrow[r], mx);
      float alpha = __expf(mrow[r] - mnew);
      mrow[r] = mnew;
      float ps = 0.f;
      #pragma unroll
      for (int ni = 0; ni < 4; ++ni) {
        float p = __expf(s[ni][r] - mnew);
        s[ni][r] = p;
        ps += p;
      }
      ps = redsum16(ps);
      lrow[r] = lrow[r] * alpha + ps;
      #pragma unroll
      for (int di = 0; di < 4; ++di) acc[di][r] *= alpha;
    }

    // P -> LDS (wave-private rows; no barrier needed before PV)
    #pragma unroll
    for (int ni = 0; ni < 4; ++ni)
      #pragma unroll
      for (int r = 0; r < 4; ++r)
        sP[(wq + lg * 4 + r) * 72 + ni * 16 + l16] = (bf16_t)s[ni][r];

    // acc += P * V
    __builtin_amdgcn_s_setprio(1);
    #pragma unroll
    for (int ks = 0; ks < 2; ++ks) {
      bf16x8 pfr, vf[4];
      pfr = *reinterpret_cast<const bf16x8*>(&sP[(wq + l16) * 72 + ks * 32 + lg * 8]);
      #pragma unroll
      for (int di = 0; di < 4; ++di)
        vf[di] = *reinterpret_cast<const bf16x8*>(&sV[cur][(di * 16 + l16) * 72 + ks * 32 + lg * 8]);
      #pragma unroll
      for (int di = 0; di < 4; ++di)
        acc[di] = __builtin_amdgcn_mfma_f32_16x16x32_bf16(pfr, vf[di], acc[di], 0, 0, 0);
    }
    __builtin_amdgcn_s_setprio(0);

    // write next tile into the alternate buffer (all waves past reading it, per top barrier)
    if (pf) stage_write(sreg, sKh[cur ^ 1], sKl[cur ^ 1], sV[cur ^ 1], tid);
    cur ^= 1;
  }

  // epilogue: normalize and store context (bf16, natural [b,s,h*64+d])
  #pragma unroll
  for (int di = 0; di < 4; ++di)
    #pragma unroll
    for (int r = 0; r < 4; ++r) {
      int qrow = q0 + wq + lg * 4 + r;
      float v = acc[di][r] / lrow[r];
      ctx[(size_t)(b * QLEN + qrow) * INNER + h * DKV + di * 16 + l16] = (bf16_t)v;
    }
}

extern "C" void kernel_launch(void* const* d_in, const int* in_sizes, int n_in,
                              void* d_out, int out_size, void* d_ws, size_t ws_size,
                              hipStream_t stream) {
  const float* X    = (const float*)d_in[0];
  const float* Wq   = (const float*)d_in[1];
  const float* Wk   = (const float*)d_in[2];
  const float* Wv   = (const float*)d_in[3];
  const float* Wo   = (const float*)d_in[4];
  const float* relb = (const float*)d_in[5];
  float* out = (float*)d_out;

  const size_t WSZ = 262144, XSZ = 2097152;
  bf16_t* ws   = (bf16_t*)d_ws;
  bf16_t* Wq_h = ws;              bf16_t* Wq_l = Wq_h + WSZ;
  bf16_t* Wk_h = Wq_l + WSZ;      bf16_t* Wk_l = Wk_h + WSZ;
  bf16_t* Wv_h = Wk_l + WSZ;      bf16_t* Wv_l = Wv_h + WSZ;
  bf16_t* Wo_h = Wv_l + WSZ;      bf16_t* Wo_l = Wo_h + WSZ;
  bf16_t* Xh   = Wo_l + WSZ;      bf16_t* Xl   = Xh + XSZ;
  bf16_t* Q_h  = Xl + XSZ;        bf16_t* Q_l  = Q_h + XSZ;
  bf16_t* K_h  = Q_l + XSZ;       bf16_t* K_l  = K_h + XSZ;
  bf16_t* Vt   = Xl;              // alias: Xl dead after K projection
  bf16_t* ctx  = Xh;              // alias: Xh dead after V projection

  dim3 tb(32, 8), tg(16, 16);
  transpose512_split<<<tg, tb, 0, stream>>>(Wq, Wq_h, Wq_l);
  transpose512_split<<<tg, tb, 0, stream>>>(Wk, Wk_h, Wk_l);
  transpose512_split<<<tg, tb, 0, stream>>>(Wv, Wv_h, Wv_l);
  transpose512_split<<<tg, tb, 0, stream>>>(Wo, Wo_h, Wo_l);

  int n4 = (2 * QLEN * DMODEL) / 4;
  cvt_split<<<n4 / 256, 256, 0, stream>>>(X, Xh, Xl, n4);

  dim3 gg(32, 4);
  gemm128_split<<<gg, 256, 0, stream>>>(Xh, Xl, Wq_h, Wq_l, Q_h, Q_l);
  gemm128_split<<<gg, 256, 0, stream>>>(Xh, Xl, Wk_h, Wk_l, K_h, K_l);
  gemm128<1><<<gg, 256, 0, stream>>>(Xh, Wv_h, Vt, nullptr);

  attn_kernel<<<dim3(32, NH, 2), 256, 0, stream>>>(Q_h, Q_l, K_h, K_l, Vt, relb, ctx);

  gemm128<2><<<gg, 256, 0, stream>>>(ctx, Wo_h, nullptr, out);
}

// Round 5
// 136.908 us; speedup vs baseline: 1.5477x; 1.2477x over previous
//
#include <hip/hip_runtime.h>
#include <hip/hip_bf16.h>
#include <cmath>

typedef __bf16 bf16_t;
typedef __bf16 bf16x8 __attribute__((ext_vector_type(8)));
typedef __bf16 bf16x4 __attribute__((ext_vector_type(4)));
typedef float f32x4 __attribute__((ext_vector_type(4)));

#define QLEN 2048
#define DMODEL 512
#define NH 8
#define DKV 64
#define INNER 512

// ---------- prep: f32 -> (hi, lo) bf16 split ----------
__global__ __launch_bounds__(256) void cvt_split(const float* __restrict__ in,
                                                 bf16_t* __restrict__ hi,
                                                 bf16_t* __restrict__ lo, int n4) {
  int i = blockIdx.x * 256 + threadIdx.x;
  if (i >= n4) return;
  float4 v = reinterpret_cast<const float4*>(in)[i];
  bf16x4 h, l;
  #pragma unroll
  for (int j = 0; j < 4; ++j) {
    float x = (&v.x)[j];
    bf16_t hb = (bf16_t)x;
    h[j] = hb;
    l[j] = (bf16_t)(x - (float)hb);
  }
  reinterpret_cast<bf16x4*>(hi)[i] = h;
  reinterpret_cast<bf16x4*>(lo)[i] = l;
}

// ---------- prep: 4 weight transposes fused: Wt[n][k] = W[k][n], hi/lo split ----------
__global__ __launch_bounds__(256) void transpose512_split_all(
    const float* __restrict__ W0, const float* __restrict__ W1,
    const float* __restrict__ W2, const float* __restrict__ W3,
    bf16_t* __restrict__ H0, bf16_t* __restrict__ L0,
    bf16_t* __restrict__ H1, bf16_t* __restrict__ L1,
    bf16_t* __restrict__ H2, bf16_t* __restrict__ L2,
    bf16_t* __restrict__ H3, bf16_t* __restrict__ L3) {
  __shared__ float tile[32][33];
  int z = blockIdx.z;
  const float* W = z == 0 ? W0 : z == 1 ? W1 : z == 2 ? W2 : W3;
  bf16_t* Whi    = z == 0 ? H0 : z == 1 ? H1 : z == 2 ? H2 : H3;
  bf16_t* Wlo    = z == 0 ? L0 : z == 1 ? L1 : z == 2 ? L2 : L3;
  int bk = blockIdx.x * 32, bn = blockIdx.y * 32;
  int tx = threadIdx.x, ty = threadIdx.y;
  #pragma unroll
  for (int i = 0; i < 32; i += 8)
    tile[ty + i][tx] = W[(size_t)(bk + ty + i) * DMODEL + bn + tx];
  __syncthreads();
  #pragma unroll
  for (int i = 0; i < 32; i += 8) {
    float v = tile[tx][ty + i];
    bf16_t hb = (bf16_t)v;
    size_t o = (size_t)(bn + ty + i) * DMODEL + bk + tx;
    Whi[o] = hb;
    Wlo[o] = (bf16_t)(v - (float)hb);
  }
}

// ---------- single-pass bf16 GEMM, BM=BN=64 (512-block dispatches) ----------
// MODE 1: bf16 transposed (V): C[(b*512+n)*2048+s]; MODE 2: f32 natural.
template<int MODE>
__global__ __launch_bounds__(256) void gemm64(const bf16_t* __restrict__ A,
                                              const bf16_t* __restrict__ Bt,
                                              bf16_t* __restrict__ Cb,
                                              float* __restrict__ Cf) {
  __shared__ bf16_t sA[64 * 72];
  __shared__ bf16_t sB[64 * 72];
  const int m0 = blockIdx.x * 64, n0 = blockIdx.y * 64;
  const int tid = threadIdx.x;
  const int lane = tid & 63, w = tid >> 6;
  const int wr = (w >> 1) * 32, wc = (w & 1) * 32;
  const int l16 = lane & 15, lg = lane >> 4;

  f32x4 acc[2][2] = {};

  for (int k0 = 0; k0 < DMODEL; k0 += 64) {
    #pragma unroll
    for (int i = 0; i < 2; ++i) {
      int chunk = tid + i * 256;           // 512 chunks of 8 bf16
      int row = chunk >> 3, c8 = (chunk & 7) * 8;
      *reinterpret_cast<bf16x8*>(&sA[row * 72 + c8]) =
          *reinterpret_cast<const bf16x8*>(&A[(size_t)(m0 + row) * DMODEL + k0 + c8]);
      *reinterpret_cast<bf16x8*>(&sB[row * 72 + c8]) =
          *reinterpret_cast<const bf16x8*>(&Bt[(size_t)(n0 + row) * DMODEL + k0 + c8]);
    }
    __syncthreads();
    #pragma unroll
    for (int ks = 0; ks < 2; ++ks) {
      bf16x8 af[2], bfr[2];
      #pragma unroll
      for (int i = 0; i < 2; ++i)
        af[i] = *reinterpret_cast<const bf16x8*>(&sA[(wr + i * 16 + l16) * 72 + ks * 32 + lg * 8]);
      #pragma unroll
      for (int j = 0; j < 2; ++j)
        bfr[j] = *reinterpret_cast<const bf16x8*>(&sB[(wc + j * 16 + l16) * 72 + ks * 32 + lg * 8]);
      #pragma unroll
      for (int i = 0; i < 2; ++i)
        #pragma unroll
        for (int j = 0; j < 2; ++j)
          acc[i][j] = __builtin_amdgcn_mfma_f32_16x16x32_bf16(af[i], bfr[j], acc[i][j], 0, 0, 0);
    }
    __syncthreads();
  }

  #pragma unroll
  for (int i = 0; i < 2; ++i)
    #pragma unroll
    for (int j = 0; j < 2; ++j)
      #pragma unroll
      for (int r = 0; r < 4; ++r) {
        int m = m0 + wr + i * 16 + lg * 4 + r;
        int n = n0 + wc + j * 16 + l16;
        float v = acc[i][j][r];
        if (MODE == 1) {
          int b = m >> 11, s = m & (QLEN - 1);
          Cb[(size_t)(b * INNER + n) * QLEN + s] = (bf16_t)v;
        } else {
          Cf[(size_t)m * DMODEL + n] = v;
        }
      }
}

// ---------- fused Q+K 3-pass split GEMM: BM=64, BN=128 over N=1024 ----------
__global__ __launch_bounds__(256) void gemm_qk_split(const bf16_t* __restrict__ Ah,
                                                     const bf16_t* __restrict__ Al,
                                                     const bf16_t* __restrict__ Bqh,
                                                     const bf16_t* __restrict__ Bql,
                                                     const bf16_t* __restrict__ Bkh,
                                                     const bf16_t* __restrict__ Bkl,
                                                     bf16_t* __restrict__ Qh,
                                                     bf16_t* __restrict__ Ql,
                                                     bf16_t* __restrict__ Kh,
                                                     bf16_t* __restrict__ Kl) {
  __shared__ bf16_t sAh[64 * 72];
  __shared__ bf16_t sAl[64 * 72];
  __shared__ bf16_t sBh[128 * 72];
  __shared__ bf16_t sBl[128 * 72];
  const int m0 = blockIdx.x * 64;
  const int n0g = blockIdx.y * 128;
  const bool isK = n0g >= 512;
  const int n0 = n0g & 511;
  const bf16_t* __restrict__ Bh = isK ? Bkh : Bqh;
  const bf16_t* __restrict__ Bl = isK ? Bkl : Bql;
  bf16_t* __restrict__ Ch = isK ? Kh : Qh;
  bf16_t* __restrict__ Cl = isK ? Kl : Ql;

  const int tid = threadIdx.x;
  const int lane = tid & 63, w = tid >> 6;
  const int wr = (w >> 1) * 32, wc = (w & 1) * 64;
  const int l16 = lane & 15, lg = lane >> 4;

  f32x4 acc[2][4] = {};

  for (int k0 = 0; k0 < DMODEL; k0 += 64) {
    #pragma unroll
    for (int i = 0; i < 2; ++i) {
      int chunk = tid + i * 256;
      int row = chunk >> 3, c8 = (chunk & 7) * 8;
      size_t ga = (size_t)(m0 + row) * DMODEL + k0 + c8;
      *reinterpret_cast<bf16x8*>(&sAh[row * 72 + c8]) = *reinterpret_cast<const bf16x8*>(&Ah[ga]);
      *reinterpret_cast<bf16x8*>(&sAl[row * 72 + c8]) = *reinterpret_cast<const bf16x8*>(&Al[ga]);
    }
    #pragma unroll
    for (int i = 0; i < 4; ++i) {
      int chunk = tid + i * 256;
      int row = chunk >> 3, c8 = (chunk & 7) * 8;
      size_t gb = (size_t)(n0 + row) * DMODEL + k0 + c8;
      *reinterpret_cast<bf16x8*>(&sBh[row * 72 + c8]) = *reinterpret_cast<const bf16x8*>(&Bh[gb]);
      *reinterpret_cast<bf16x8*>(&sBl[row * 72 + c8]) = *reinterpret_cast<const bf16x8*>(&Bl[gb]);
    }
    __syncthreads();
    #pragma unroll
    for (int ks = 0; ks < 2; ++ks) {
      bf16x8 ah[2], al[2], bh[4], bl[4];
      #pragma unroll
      for (int i = 0; i < 2; ++i) {
        int ro = (wr + i * 16 + l16) * 72 + ks * 32 + lg * 8;
        ah[i] = *reinterpret_cast<const bf16x8*>(&sAh[ro]);
        al[i] = *reinterpret_cast<const bf16x8*>(&sAl[ro]);
      }
      #pragma unroll
      for (int j = 0; j < 4; ++j) {
        int ro = (wc + j * 16 + l16) * 72 + ks * 32 + lg * 8;
        bh[j] = *reinterpret_cast<const bf16x8*>(&sBh[ro]);
        bl[j] = *reinterpret_cast<const bf16x8*>(&sBl[ro]);
      }
      #pragma unroll
      for (int i = 0; i < 2; ++i)
        #pragma unroll
        for (int j = 0; j < 4; ++j) {
          acc[i][j] = __builtin_amdgcn_mfma_f32_16x16x32_bf16(ah[i], bh[j], acc[i][j], 0, 0, 0);
          acc[i][j] = __builtin_amdgcn_mfma_f32_16x16x32_bf16(ah[i], bl[j], acc[i][j], 0, 0, 0);
          acc[i][j] = __builtin_amdgcn_mfma_f32_16x16x32_bf16(al[i], bh[j], acc[i][j], 0, 0, 0);
        }
    }
    __syncthreads();
  }

  #pragma unroll
  for (int i = 0; i < 2; ++i)
    #pragma unroll
    for (int j = 0; j < 4; ++j)
      #pragma unroll
      for (int r = 0; r < 4; ++r) {
        int m = m0 + wr + i * 16 + lg * 4 + r;
        int n = n0 + wc + j * 16 + l16;
        float v = acc[i][j][r];
        bf16_t hb = (bf16_t)v;
        size_t o = (size_t)m * INNER + n;
        Ch[o] = hb;
        Cl[o] = (bf16_t)(v - (float)hb);
      }
}

// ---------- attention helpers ----------
__device__ __forceinline__ float redmax16(float v) {
  v = fmaxf(v, __shfl_xor(v, 1));
  v = fmaxf(v, __shfl_xor(v, 2));
  v = fmaxf(v, __shfl_xor(v, 4));
  v = fmaxf(v, __shfl_xor(v, 8));
  return v;
}
__device__ __forceinline__ float redsum16(float v) {
  v += __shfl_xor(v, 1);
  v += __shfl_xor(v, 2);
  v += __shfl_xor(v, 4);
  v += __shfl_xor(v, 8);
  return v;
}
__device__ __forceinline__ int t5_bucket_abs(int n) {
  if (n < 8)  return n;
  if (n < 12) return 8;
  if (n < 16) return 9;
  if (n < 23) return 10;
  if (n < 32) return 11;
  if (n < 46) return 12;
  if (n < 64) return 13;
  if (n < 91) return 14;
  return 15;
}

// ---------- flash attention v3: single-buffer LDS (36.6KB -> 4 blocks/CU) ----------
#define SPS 68   // sP stride: 2*68 B row stride == 8 banks -> lg groups disjoint

struct StageRegs { bf16x8 kh[2], kl[2], v[2]; };

__device__ __forceinline__ void stage_load(StageRegs& r, const bf16_t* __restrict__ Kh,
                                           const bf16_t* __restrict__ Kl,
                                           const bf16_t* __restrict__ Vt,
                                           int b, int h, int k0, int tid) {
  #pragma unroll
  for (int i = 0; i < 2; ++i) {
    int chunk = tid + i * 256;
    int row = chunk >> 3, c8 = (chunk & 7) * 8;
    size_t gk = (size_t)(b * QLEN + k0 + row) * INNER + h * DKV + c8;
    r.kh[i] = *reinterpret_cast<const bf16x8*>(&Kh[gk]);
    r.kl[i] = *reinterpret_cast<const bf16x8*>(&Kl[gk]);
    r.v[i]  = *reinterpret_cast<const bf16x8*>(
        &Vt[(size_t)((b * NH + h) * DKV + row) * QLEN + k0 + c8]);
  }
}
__device__ __forceinline__ void stage_write(const StageRegs& r, bf16_t* dKh, bf16_t* dKl,
                                            bf16_t* dV, int tid) {
  #pragma unroll
  for (int i = 0; i < 2; ++i) {
    int chunk = tid + i * 256;
    int row = chunk >> 3, c8 = (chunk & 7) * 8;
    *reinterpret_cast<bf16x8*>(&dKh[row * 72 + c8]) = r.kh[i];
    *reinterpret_cast<bf16x8*>(&dKl[row * 72 + c8]) = r.kl[i];
    *reinterpret_cast<bf16x8*>(&dV [row * 72 + c8]) = r.v[i];
  }
}

__global__ __launch_bounds__(256) void attn_kernel(const bf16_t* __restrict__ Qh,
                                                   const bf16_t* __restrict__ Ql,
                                                   const bf16_t* __restrict__ Kh,
                                                   const bf16_t* __restrict__ Kl,
                                                   const bf16_t* __restrict__ Vt,
                                                   const float* __restrict__ relb,
                                                   bf16_t* __restrict__ ctx) {
  __shared__ bf16_t sKh[64 * 72];
  __shared__ bf16_t sKl[64 * 72];
  __shared__ bf16_t sV [64 * 72];
  __shared__ bf16_t sP [64 * SPS];
  __shared__ float sBiasH[32];

  // XCD-aware swizzle: 512 blocks = 8 XCDs x 64; give each XCD contiguous
  // q-tiles of the same (b,h) so its L2 holds 2 K/V sets (1.5MB < 4MB).
  const int id = blockIdx.x;
  const int lin = (id & 7) * 64 + (id >> 3);
  const int qt = lin & 31, h = (lin >> 5) & 7, b = lin >> 8;

  const int tid = threadIdx.x, lane = tid & 63, w = tid >> 6;
  const int l16 = lane & 15, lg = lane >> 4;
  const int q0 = qt * 64;
  const int wq = w * 16;   // wave-owned q rows [wq, wq+16)

  if (tid < 32) sBiasH[tid] = relb[tid * NH + h];

  bf16x8 qh[2], ql[2];
  #pragma unroll
  for (int ks = 0; ks < 2; ++ks) {
    size_t o = (size_t)(b * QLEN + q0 + wq + l16) * INNER + h * DKV + ks * 32 + lg * 8;
    qh[ks] = *reinterpret_cast<const bf16x8*>(&Qh[o]);
    ql[ks] = *reinterpret_cast<const bf16x8*>(&Ql[o]);
  }

  f32x4 acc[4] = {};
  float mrow[4], lrow[4];
  #pragma unroll
  for (int r = 0; r < 4; ++r) { mrow[r] = -INFINITY; lrow[r] = 0.f; }

  const int NT = QLEN / 64;
  StageRegs sreg;
  stage_load(sreg, Kh, Kl, Vt, b, h, 0, tid);
  stage_write(sreg, sKh, sKl, sV, tid);
  __syncthreads();

  for (int kt = 0; kt < NT; ++kt) {
    const int k0 = kt * 64;
    const bool pf = (kt + 1 < NT);
    if (pf) stage_load(sreg, Kh, Kl, Vt, b, h, k0 + 64, tid);  // in flight during compute

    // S = Q K^T in 3 passes (hi*hi + hi*lo + lo*hi)
    f32x4 s[4] = {};
    __builtin_amdgcn_s_setprio(1);
    #pragma unroll
    for (int ks = 0; ks < 2; ++ks) {
      bf16x8 kh[4], kl[4];
      #pragma unroll
      for (int ni = 0; ni < 4; ++ni) {
        int ro = (ni * 16 + l16) * 72 + ks * 32 + lg * 8;
        kh[ni] = *reinterpret_cast<const bf16x8*>(&sKh[ro]);
        kl[ni] = *reinterpret_cast<const bf16x8*>(&sKl[ro]);
      }
      #pragma unroll
      for (int ni = 0; ni < 4; ++ni) {
        s[ni] = __builtin_amdgcn_mfma_f32_16x16x32_bf16(qh[ks], kh[ni], s[ni], 0, 0, 0);
        s[ni] = __builtin_amdgcn_mfma_f32_16x16x32_bf16(qh[ks], kl[ni], s[ni], 0, 0, 0);
        s[ni] = __builtin_amdgcn_mfma_f32_16x16x32_bf16(ql[ks], kh[ni], s[ni], 0, 0, 0);
      }
    }
    __builtin_amdgcn_s_setprio(0);

    // + relative position bias
    const int dmin = q0 - (k0 + 63);
    const int dmax = q0 + 63 - k0;
    if (dmin >= 91) {
      const float bias = sBiasH[15];
      #pragma unroll
      for (int ni = 0; ni < 4; ++ni)
        #pragma unroll
        for (int r = 0; r < 4; ++r) s[ni][r] += bias;
    } else if (dmax <= -91) {
      const float bias = sBiasH[31];
      #pragma unroll
      for (int ni = 0; ni < 4; ++ni)
        #pragma unroll
        for (int r = 0; r < 4; ++r) s[ni][r] += bias;
    } else {
      #pragma unroll
      for (int ni = 0; ni < 4; ++ni) {
        int kcol = k0 + ni * 16 + l16;
        #pragma unroll
        for (int r = 0; r < 4; ++r) {
          int qrow = q0 + wq + lg * 4 + r;
          int d = qrow - kcol;
          int n = d < 0 ? -d : d;
          int bk = t5_bucket_abs(n) + (d < 0 ? 16 : 0);
          s[ni][r] += sBiasH[bk];
        }
      }
    }

    // online softmax (rows live in 16-lane groups)
    #pragma unroll
    for (int r = 0; r < 4; ++r) {
      float mx = fmaxf(fmaxf(s[0][r], s[1][r]), fmaxf(s[2][r], s[3][r]));
      mx = redmax16(mx);
      float mnew = fmaxf(mrow[r], mx);
      float alpha = __expf(mrow[r] - mnew);
      mrow[r] = mnew;
      float ps = 0.f;
      #pragma unroll
      for (int ni = 0; ni < 4; ++ni) {
        float p = __expf(s[ni][r] - mnew);
        s[ni][r] = p;
        ps += p;
      }
      ps = redsum16(ps);
      lrow[r] = lrow[r] * alpha + ps;
      #pragma unroll
      for (int di = 0; di < 4; ++di) acc[di][r] *= alpha;
    }

    // P -> LDS (wave-private rows; stride 68 -> lg groups on disjoint bank octets)
    #pragma unroll
    for (int ni = 0; ni < 4; ++ni)
      #pragma unroll
      for (int r = 0; r < 4; ++r)
        sP[(wq + lg * 4 + r) * SPS + ni * 16 + l16] = (bf16_t)s[ni][r];

    // acc += P * V
    __builtin_amdgcn_s_setprio(1);
    #pragma unroll
    for (int ks = 0; ks < 2; ++ks) {
      bf16x8 pfr, vf[4];
      pfr = *reinterpret_cast<const bf16x8*>(&sP[(wq + l16) * SPS + ks * 32 + lg * 8]);
      #pragma unroll
      for (int di = 0; di < 4; ++di)
        vf[di] = *reinterpret_cast<const bf16x8*>(&sV[(di * 16 + l16) * 72 + ks * 32 + lg * 8]);
      #pragma unroll
      for (int di = 0; di < 4; ++di)
        acc[di] = __builtin_amdgcn_mfma_f32_16x16x32_bf16(pfr, vf[di], acc[di], 0, 0, 0);
    }
    __builtin_amdgcn_s_setprio(0);

    __syncthreads();                 // all waves done reading this tile
    if (pf) stage_write(sreg, sKh, sKl, sV, tid);
    __syncthreads();                 // next tile visible
  }

  // epilogue
  #pragma unroll
  for (int di = 0; di < 4; ++di)
    #pragma unroll
    for (int r = 0; r < 4; ++r) {
      int qrow = q0 + wq + lg * 4 + r;
      float v = acc[di][r] / lrow[r];
      ctx[(size_t)(b * QLEN + qrow) * INNER + h * DKV + di * 16 + l16] = (bf16_t)v;
    }
}

extern "C" void kernel_launch(void* const* d_in, const int* in_sizes, int n_in,
                              void* d_out, int out_size, void* d_ws, size_t ws_size,
                              hipStream_t stream) {
  const float* X    = (const float*)d_in[0];
  const float* Wq   = (const float*)d_in[1];
  const float* Wk   = (const float*)d_in[2];
  const float* Wv   = (const float*)d_in[3];
  const float* Wo   = (const float*)d_in[4];
  const float* relb = (const float*)d_in[5];
  float* out = (float*)d_out;

  const size_t WSZ = 262144, XSZ = 2097152;
  bf16_t* ws   = (bf16_t*)d_ws;
  bf16_t* Wq_h = ws;              bf16_t* Wq_l = Wq_h + WSZ;
  bf16_t* Wk_h = Wq_l + WSZ;      bf16_t* Wk_l = Wk_h + WSZ;
  bf16_t* Wv_h = Wk_l + WSZ;      bf16_t* Wv_l = Wv_h + WSZ;
  bf16_t* Wo_h = Wv_l + WSZ;      bf16_t* Wo_l = Wo_h + WSZ;
  bf16_t* Xh   = Wo_l + WSZ;      bf16_t* Xl   = Xh + XSZ;
  bf16_t* Q_h  = Xl + XSZ;        bf16_t* Q_l  = Q_h + XSZ;
  bf16_t* K_h  = Q_l + XSZ;       bf16_t* K_l  = K_h + XSZ;
  bf16_t* Vt   = Xl;              // alias: Xl dead after QK projection
  bf16_t* ctx  = Xh;              // alias: Xh dead after V projection

  transpose512_split_all<<<dim3(16, 16, 4), dim3(32, 8), 0, stream>>>(
      Wq, Wk, Wv, Wo, Wq_h, Wq_l, Wk_h, Wk_l, Wv_h, Wv_l, Wo_h, Wo_l);

  int n4 = (2 * QLEN * DMODEL) / 4;
  cvt_split<<<n4 / 256, 256, 0, stream>>>(X, Xh, Xl, n4);

  gemm_qk_split<<<dim3(64, 8), 256, 0, stream>>>(Xh, Xl, Wq_h, Wq_l, Wk_h, Wk_l,
                                                 Q_h, Q_l, K_h, K_l);
  gemm64<1><<<dim3(64, 8), 256, 0, stream>>>(Xh, Wv_h, Vt, nullptr);

  attn_kernel<<<dim3(512), 256, 0, stream>>>(Q_h, Q_l, K_h, K_l, Vt, relb, ctx);

  gemm64<2><<<dim3(64, 8), 256, 0, stream>>>(ctx, Wo_h, nullptr, out);
}